// Round 9
// baseline (661.575 us; speedup 1.0000x reference)
//
#include <hip/hip_runtime.h>
#include <hip/hip_bf16.h>

#define N 8192
#define D 128
#define INV_T 14.285714285714286f   // 1/0.07
#define LDS_PITCH 136               // bf16 elems; 272 B row stride

typedef __bf16 v8bf __attribute__((ext_vector_type(8)));
typedef __bf16 v4bf __attribute__((ext_vector_type(4)));
typedef float  v4f  __attribute__((ext_vector_type(4)));

// ---------------- Kernel 0: pack int32 0/1 masks -> bitmasks (32x smaller) -----
// Pure streaming shape (m13): grid-stride, no LDS, low VGPR, int4 loads.
// pbits[i*1024 + b] bit k  <=>  pmask[i, 8b+k] != 0   (little-endian bytes)
__global__ __launch_bounds__(256) void pack_masks(
    const int* __restrict__ pmask, const int* __restrict__ nmask,
    unsigned char* __restrict__ pbits, unsigned char* __restrict__ nbits)
{
    const int nthreads = gridDim.x * blockDim.x;
    const int total = N * N / 8;           // 8,388,608 byte-units
    for (int t = blockIdx.x * blockDim.x + threadIdx.x; t < total; t += nthreads) {
        const size_t e = (size_t)t * 8;
        const int4 a0 = *reinterpret_cast<const int4*>(pmask + e);
        const int4 a1 = *reinterpret_cast<const int4*>(pmask + e + 4);
        const int4 b0 = *reinterpret_cast<const int4*>(nmask + e);
        const int4 b1 = *reinterpret_cast<const int4*>(nmask + e + 4);
        unsigned pb = (unsigned)(a0.x != 0)        | ((unsigned)(a0.y != 0) << 1)
                    | ((unsigned)(a0.z != 0) << 2) | ((unsigned)(a0.w != 0) << 3)
                    | ((unsigned)(a1.x != 0) << 4) | ((unsigned)(a1.y != 0) << 5)
                    | ((unsigned)(a1.z != 0) << 6) | ((unsigned)(a1.w != 0) << 7);
        unsigned nb = (unsigned)(b0.x != 0)        | ((unsigned)(b0.y != 0) << 1)
                    | ((unsigned)(b0.z != 0) << 2) | ((unsigned)(b0.w != 0) << 3)
                    | ((unsigned)(b1.x != 0) << 4) | ((unsigned)(b1.y != 0) << 5)
                    | ((unsigned)(b1.z != 0) << 6) | ((unsigned)(b1.w != 0) << 7);
        pbits[t] = (unsigned char)pb;
        nbits[t] = (unsigned char)nb;
    }
}

// ---------------- Kernel 1: row-normalize fp32 -> bf16 ----------------
__global__ __launch_bounds__(256) void normalize_kernel(
    const float* __restrict__ f, __bf16* __restrict__ out)
{
    int gwave = (blockIdx.x * blockDim.x + threadIdx.x) >> 6;  // row id
    int lane  = threadIdx.x & 63;
    const float2 v = *reinterpret_cast<const float2*>(f + (size_t)gwave * D + lane * 2);
    float ss = v.x * v.x + v.y * v.y;
    #pragma unroll
    for (int m = 32; m; m >>= 1) ss += __shfl_xor(ss, m);
    float inv = 1.0f / fmaxf(sqrtf(ss), 1e-8f);
    __bf16* o = out + (size_t)gwave * D + lane * 2;
    o[0] = (__bf16)(v.x * inv);
    o[1] = (__bf16)(v.y * inv);
}

// ---------------- Kernel 2: Gram tile -> exp -> LDS -> bitmask reduce ----------
// Mask traffic is now 16B/row/half-wave from L2-resident bitmasks (was 1KB from
// HBM) — the stream that pinned R1..R7 at ~250us is gone.
__global__ __launch_bounds__(256) void supcon_main(
    const __bf16* __restrict__ F,
    const unsigned char* __restrict__ pbits, const unsigned char* __restrict__ nbits,
    float* __restrict__ pos, float* __restrict__ neg)
{
    __shared__ __bf16 E[128 * LDS_PITCH];   // 34816 B -> 4 blocks/CU

    const int tid  = threadIdx.x;
    const int lane = tid & 63;
    const int wid  = tid >> 6;       // 0..3
    const int wr   = wid >> 1, wc = wid & 1;
    const int i0   = blockIdx.y * 128;
    const int j0   = blockIdx.x * 128;
    const int iw   = i0 + wr * 64;
    const int jw   = j0 + wc * 64;
    const int r    = lane & 15;
    const int q    = lane >> 4;      // 0..3

    v4f acc[4][4];
    #pragma unroll
    for (int m = 0; m < 4; ++m)
        #pragma unroll
        for (int n = 0; n < 4; ++n) acc[m][n] = (v4f)0.0f;

    // ---- MFMA: K = 128 in 4 steps of 32 (fragments straight from global; F is L2-resident)
    #pragma unroll
    for (int ks = 0; ks < 4; ++ks) {
        v8bf a[4], b[4];
        #pragma unroll
        for (int m = 0; m < 4; ++m)
            a[m] = *reinterpret_cast<const v8bf*>(F + (size_t)(iw + m * 16 + r) * D + ks * 32 + q * 8);
        #pragma unroll
        for (int n = 0; n < 4; ++n)
            b[n] = *reinterpret_cast<const v8bf*>(F + (size_t)(jw + n * 16 + r) * D + ks * 32 + q * 8);
        #pragma unroll
        for (int m = 0; m < 4; ++m)
            #pragma unroll
            for (int n = 0; n < 4; ++n)
                acc[m][n] = __builtin_amdgcn_mfma_f32_16x16x32_bf16(a[m], b[n], acc[m][n], 0, 0, 0);
    }

    // ---- exp + diagonal kill + bf16 store to LDS
    const bool diag = (blockIdx.x == blockIdx.y);
    #pragma unroll
    for (int m = 0; m < 4; ++m) {
        #pragma unroll
        for (int n = 0; n < 4; ++n) {
            const int colL = wc * 64 + n * 16 + r;
            #pragma unroll
            for (int v = 0; v < 4; ++v) {
                const int rowL = wr * 64 + m * 16 + q * 4 + v;
                float e = __expf(acc[m][n][v] * INV_T);
                if (diag && rowL == colL) e = 0.0f;
                E[rowL * LDS_PITCH + colL] = (__bf16)e;
            }
        }
    }
    __syncthreads();

    // ---- bitmask reduce: wave owns 32 rows, half-wave (32 lanes) per row.
    // Lane c covers cols j0+4c..j0+4c+3: uint32 word (c>>3) of the row's 128-bit
    // window, nibble (c&7)*4.
    const int half = lane >> 5;
    const int c    = lane & 31;
    const int row0 = wid * 32 + half;
    const int wsel = (c >> 3) << 2;          // byte offset of uint32 word
    const int nib  = (c & 7) * 4;
    float pacc[16], gacc[16];

    #pragma unroll
    for (int it = 0; it < 16; ++it) {
        const int row = row0 + 2 * it;
        const int gi  = i0 + row;
        const size_t bb = (size_t)gi * (N / 8) + (j0 >> 3) + wsel;
        const unsigned pw = *reinterpret_cast<const unsigned*>(pbits + bb);
        const unsigned nw = *reinterpret_cast<const unsigned*>(nbits + bb);
        const unsigned pn = (pw >> nib) & 0xFu;
        const unsigned nn = (nw >> nib) & 0xFu;
        const v4bf ev = *reinterpret_cast<const v4bf*>(&E[row * LDS_PITCH + c * 4]);
        const float e0 = (float)ev[0], e1 = (float)ev[1];
        const float e2 = (float)ev[2], e3 = (float)ev[3];
        pacc[it] = ((pn & 1u) ? e0 : 0.0f) + ((pn & 2u) ? e1 : 0.0f)
                 + ((pn & 4u) ? e2 : 0.0f) + ((pn & 8u) ? e3 : 0.0f);
        gacc[it] = ((nn & 1u) ? e0 : 0.0f) + ((nn & 2u) ? e1 : 0.0f)
                 + ((nn & 4u) ? e2 : 0.0f) + ((nn & 8u) ? e3 : 0.0f);
    }

    // ---- final reductions (independent shfl trees), then atomic burst.
    #pragma unroll
    for (int it = 0; it < 16; ++it) {
        float p = pacc[it], g = gacc[it];
        #pragma unroll
        for (int msk = 1; msk < 32; msk <<= 1) {   // xor<32 stays within each half
            p += __shfl_xor(p, msk);
            g += __shfl_xor(g, msk);
        }
        if (c == 0) {
            const int gi = i0 + row0 + it * 2;
            atomicAdd(&pos[gi], p);
            atomicAdd(&neg[gi], g);
        }
    }
}

// ---------------- Kernel 3: loss = -mean(log(pos/(pos+neg))) ----------------
__global__ __launch_bounds__(1024) void finalize_kernel(
    const float* __restrict__ pos, const float* __restrict__ neg, float* __restrict__ out)
{
    __shared__ float sm[16];
    int tid = threadIdx.x;
    float acc = 0.0f;
    for (int i = tid; i < N; i += 1024) {
        float p = pos[i], g = neg[i];
        acc += logf(p / (p + g));
    }
    #pragma unroll
    for (int m = 32; m; m >>= 1) acc += __shfl_xor(acc, m);
    if ((tid & 63) == 0) sm[tid >> 6] = acc;
    __syncthreads();
    if (tid == 0) {
        float t = 0.0f;
        #pragma unroll
        for (int w = 0; w < 16; ++w) t += sm[w];
        out[0] = -t * (1.0f / (float)N);
    }
}

extern "C" void kernel_launch(void* const* d_in, const int* in_sizes, int n_in,
                              void* d_out, int out_size, void* d_ws, size_t ws_size,
                              hipStream_t stream) {
    const float* feat  = (const float*)d_in[0];
    const int*   pmask = (const int*)d_in[1];
    const int*   nmask = (const int*)d_in[2];
    float* out = (float*)d_out;

    char* ws = (char*)d_ws;
    __bf16* fnb = (__bf16*)ws;                                   // [0, 2MB)
    float*  pos = (float*)(ws + (size_t)2 * 1024 * 1024);        // 32 KB
    float*  neg = pos + N;                                       // 32 KB
    unsigned char* pbits = (unsigned char*)(ws + (size_t)4 * 1024 * 1024);   // 8 MB
    unsigned char* nbits = (unsigned char*)(ws + (size_t)12 * 1024 * 1024);  // 8 MB

    hipMemsetAsync(pos, 0, 2 * N * sizeof(float), stream);

    pack_masks<<<dim3(2048), 256, 0, stream>>>(pmask, nmask, pbits, nbits);
    normalize_kernel<<<dim3(N / 4), 256, 0, stream>>>(feat, fnb);

    dim3 grid(N / 128, N / 128);
    supcon_main<<<grid, 256, 0, stream>>>(fnb, pbits, nbits, pos, neg);

    finalize_kernel<<<1, 1024, 0, stream>>>(pos, neg, out);
}